// Round 18
// baseline (43.094 us; speedup 1.0000x reference)
//
#include <hip/hip_runtime.h>
#include <hip/hip_bf16.h>

#define BATCH 16
#define CIN   128
#define HIMG  56
#define WIMG  56
#define NPIX  (HIMG*WIMG)      // 3136
#define CS    256
#define NQ    4
#define HOUT  28
#define WOUT  28
#define NOPIX (HOUT*WOUT)      // 784
#define QSCALE 0.17677669529663687f   // hc^-0.5 = 1/sqrt(32)
#define NCOL  288              // 256 V cols + 32 qk cols

typedef __attribute__((ext_vector_type(8))) short    bf16x8;
typedef __attribute__((ext_vector_type(4))) float    f32x4;
typedef __attribute__((ext_vector_type(4))) unsigned u32x4;

static __device__ __forceinline__ unsigned short f2bf(float f) {
    return __builtin_bit_cast(unsigned short, __float2bfloat16(f));
}
static __device__ __forceinline__ float bf2f(unsigned short u) {
    return __builtin_bit_cast(float, (unsigned)u << 16);
}
static __device__ __forceinline__ unsigned int pack2(float a, float b) {
    return (unsigned)f2bf(a) | ((unsigned)f2bf(b) << 16);
}

// ---------- kernel W: all weight prep, parallel (r17-exact) ----------
__global__ __launch_bounds__(256) void kW_prep(
    const float* __restrict__ Wout, const float* __restrict__ Wk,
    const float* __restrict__ Wv,   const float* __restrict__ qp,
    unsigned short* __restrict__ WB, unsigned short* __restrict__ Wp)
{
    __shared__ float buf[4736];   // 18.9 KB, aliased per block role
    const int t   = threadIdx.x;
    const int blk = blockIdx.x;
    char* wp = (char*)Wp;

    if (blk < 8) {
        // ---- Wout -> bf16, coalesced ----
        const size_t base = (size_t)blk * 8192 + t;
        #pragma unroll
        for (int i = 0; i < 32; ++i)
            WB[base + i*256] = f2bf(Wout[base + i*256]);
    } else if (blk < 16) {
        // ---- WvT repack: W' row ch holds Wv[*, ch] as bf16 pairs, XOR-swizzled ----
        float (*lt)[33] = (float(*)[33])buf;           // 128*33 = 4224
        const int ch0 = (blk - 8) * 32;
        const int j = t & 31, r = t >> 5;              // r = 0..7
        #pragma unroll
        for (int pass = 0; pass < 16; ++pass) {
            const int c = r + pass*8;
            lt[c][j] = Wv[(size_t)c*CS + ch0 + j];     // coalesced 128B/row
        }
        __syncthreads();
        const int lch = t >> 3, sub = t & 7;
        const int ch  = ch0 + lch;
        const int mask = (ch & 7) << 4;
        #pragma unroll
        for (int i = 0; i < 8; ++i) {
            const int c2 = sub*8 + i;
            const unsigned u = pack2(lt[2*c2][lch], lt[2*c2+1][lch]);
            *(unsigned*)(wp + ch*256 + ((c2*4) ^ mask)) = u;
        }
    } else {
        // ---- fold for head h: Wq'[q*8+h][c] = sum_j Wk[c][h*32+j]*q[q][h*32+j]*QSCALE
        const int h = blk - 16;
        float (*wt)[36] = (float(*)[36])buf;           // 128 x 36 pad
        float* qlds = buf + 4608;                      // 4 x 32
        if (t < 128) qlds[t] = qp[(t >> 5)*CS + h*32 + (t & 31)] * QSCALE;
        {   // stage 128 rows x 32 floats, coalesced
            const int r0 = t >> 5, col = t & 31;
            #pragma unroll
            for (int pass = 0; pass < 16; ++pass) {
                const int c = r0 + pass*8;
                wt[c][col] = Wk[(size_t)c*CS + h*32 + col];
            }
        }
        __syncthreads();

        const int q  = t >> 6, c2 = t & 63;
        const int qh = q*8 + h;
        const float* r0 = wt[2*c2];
        const float* r1 = wt[2*c2 + 1];
        const float* qv = qlds + q*32;
        float d0 = 0.f, d1 = 0.f;
        #pragma unroll
        for (int j4 = 0; j4 < 32; j4 += 4) {
            const float4 a0 = *(const float4*)(r0 + j4);
            const float4 a1 = *(const float4*)(r1 + j4);
            const float4 qq = *(const float4*)(qv + j4);
            d0 = fmaf(a0.x, qq.x, d0); d0 = fmaf(a0.y, qq.y, d0);
            d0 = fmaf(a0.z, qq.z, d0); d0 = fmaf(a0.w, qq.w, d0);
            d1 = fmaf(a1.x, qq.x, d1); d1 = fmaf(a1.y, qq.y, d1);
            d1 = fmaf(a1.z, qq.z, d1); d1 = fmaf(a1.w, qq.w, d1);
        }
        *(unsigned*)(wp + (256 + qh)*256 + ((c2*4) ^ (h << 4))) = pack2(d0, d1);
    }
}

// ---------- kernel 1: fused transpose+GEMM (r11 structure, async LDS staging) ----------
// Staging now uses global_load_lds (direct-to-LDS DMA, 16B/lane): no VGPR
// round-trip, no ds_write phase; A-pack VALU overlaps in-flight staging.
// LDS dest is wave-uniform base + lane*16 (linear layout) as required.
__global__ __launch_bounds__(512, 4) void k1_mfma(
    const float* __restrict__ x, const unsigned short* __restrict__ Wp,
    float* __restrict__ costO, unsigned short* __restrict__ Vout)
{
    __shared__ unsigned short Blds[NCOL*CIN];   // 73728 B

    const int t    = threadIdx.x;               // 0..511
    const int lane = t & 63;
    const int w    = t >> 6;                    // 0..7
    const int l15  = lane & 15;
    const int hi   = lane >> 4;
    const int gp0  = blockIdx.x * 128;          // global pixel base (may cross batch)
    const int gw   = gp0 + w*16;                // wave's 16-pixel row base
    const int b    = gw / NPIX;                 // 16 | NPIX, so wave stays in-batch
    const int p    = gw - b*NPIX + l15;

    // issue A loads (32 dwords, 16-lane coalesced into 64B sectors)
    float av[4][8];
    {
        const float* xb = x + (size_t)b*CIN*NPIX + (size_t)(hi*8)*NPIX + p;
        #pragma unroll
        for (int s = 0; s < 4; ++s)
            #pragma unroll
            for (int j = 0; j < 8; ++j)
                av[s][j] = xb[(size_t)(s*32 + j)*NPIX];
    }

    {   // stage B: async direct-to-LDS copy of pre-swizzled image, 9 x 16B/thread
        #pragma unroll
        for (int i = 0; i < 9; ++i) {
            const unsigned short* src = Wp   + (size_t)(t + i*512)*8;
            unsigned short*       dst = Blds + (size_t)(t + i*512)*8;
            __builtin_amdgcn_global_load_lds(
                (const __attribute__((address_space(1))) unsigned int*)src,
                (__attribute__((address_space(3))) unsigned int*)dst,
                16, 0, 0);
        }
    }

    // pack A to bf16 frags while staging is in flight
    bf16x8 afr[4];
    #pragma unroll
    for (int s = 0; s < 4; ++s) {
        u32x4 u;
        u[0] = pack2(av[s][0], av[s][1]);
        u[1] = pack2(av[s][2], av[s][3]);
        u[2] = pack2(av[s][4], av[s][5]);
        u[3] = pack2(av[s][6], av[s][7]);
        afr[s] = __builtin_bit_cast(bf16x8, u);
    }
    __syncthreads();

    f32x4 acc[18];
    #pragma unroll
    for (int n = 0; n < 18; ++n) acc[n] = (f32x4){0.f,0.f,0.f,0.f};

    const int   mask  = (l15 & 7) << 4;
    const char* bbase = (const char*)Blds + l15*256;

    #pragma unroll
    for (int s = 0; s < 4; ++s) {
        const char* bs = bbase + ((s*64 + hi*16) ^ mask);
        #pragma unroll
        for (int n = 0; n < 18; ++n) {
            const bf16x8 bfr = *(const bf16x8*)(bs + n*4096);
            acc[n] = __builtin_amdgcn_mfma_f32_16x16x32_bf16(afr[s], bfr, acc[n], 0, 0, 0);
        }
    }

    const size_t prow0 = (size_t)gw + hi*4;
    #pragma unroll
    for (int n = 0; n < 16; ++n) {          // V cols, bf16
        unsigned short* vp = Vout + prow0*CS + n*16 + l15;
        #pragma unroll
        for (int r = 0; r < 4; ++r)
            vp[(size_t)r*CS] = f2bf(acc[n][r]);
    }
    #pragma unroll
    for (int n = 16; n < 18; ++n) {         // qk cols -> cost = exp(qk)
        float* cp = costO + prow0*32 + (n-16)*16 + l15;
        #pragma unroll
        for (int r = 0; r < 4; ++r)
            cp[(size_t)r*32] = __expf(acc[n][r]);
    }
}

// ---------- kernel 23: fused aggregation + projection (r17-exact) ----------
__global__ __launch_bounds__(512) void k23_fused(
    const float* __restrict__ cost, const unsigned short* __restrict__ V,
    const float* __restrict__ ascale, const float* __restrict__ rpb,
    const unsigned short* __restrict__ WB, float* __restrict__ out)
{
    __shared__ __align__(16) char plds[32*512];   // 16 KB pre-tile

    const int t    = threadIdx.x;
    const int lane = t & 63;
    const int w    = t >> 6;
    // bijective XCD swizzle: 392 blocks, 49 contiguous per XCD (~2 batches' V)
    const int bid  = blockIdx.x;
    const int rb   = (bid & 7) * 49 + (bid >> 3);
    const int gp0  = rb * 32;
    const int qh   = lane & 31;

    // ---- phase 1: aggregate 4 pixels per wave ----
    #pragma unroll
    for (int i = 0; i < 4; ++i) {
        const int lp  = w*4 + i;
        const int gp  = gp0 + lp;
        const int b   = gp / NOPIX;
        const int rem = gp - b*NOPIX;
        const int ho  = rem / WOUT, wo = rem - (rem/WOUT)*WOUT;

        int pk[9];
        #pragma unroll
        for (int k = 0; k < 9; ++k) {
            const int y  = 2*ho - 1 + k/3;
            const int xx = 2*wo - 1 + k%3;
            const bool v = ((unsigned)y < (unsigned)HIMG) && ((unsigned)xx < (unsigned)WIMG);
            pk[k] = v ? (y*WIMG + xx) : -1;
        }

        float cp[9];
        float den = 0.f;
        #pragma unroll
        for (int k = 0; k < 9; ++k) {
            const float s  = (pk[k] >= 0) ? cost[((size_t)(b*NPIX) + pk[k])*32 + qh] : 0.f;
            const float wd = __expf(rpb[k*32 + qh]);
            den   = fmaf(wd, s, den);
            cp[k] = wd * ascale[k*32 + qh] * s;
        }
        const float rden = 1.f / den;

        float coef[9];
        #pragma unroll
        for (int k = 0; k < 9; ++k) {
            float v = cp[k] * rden;
            v += __shfl_xor(v, 8);
            v += __shfl_xor(v, 16);
            coef[k] = __shfl(v, lane >> 3);    // lane's head h = (lane*4)/32 = lane>>3
        }

        float a0 = 0.f, a1 = 0.f, a2 = 0.f, a3 = 0.f;
        #pragma unroll
        for (int k = 0; k < 9; ++k) {
            const int p = (pk[k] >= 0) ? pk[k] : 0;   // coef==0 for invalid taps
            const ushort4 v4 = *(const ushort4*)(V + ((size_t)(b*NPIX) + p)*CS + lane*4);
            a0 = fmaf(coef[k], bf2f(v4.x), a0);
            a1 = fmaf(coef[k], bf2f(v4.y), a1);
            a2 = fmaf(coef[k], bf2f(v4.z), a2);
            a3 = fmaf(coef[k], bf2f(v4.w), a3);
        }
        ushort4 o4;
        o4.x = f2bf(a0); o4.y = f2bf(a1); o4.z = f2bf(a2); o4.w = f2bf(a3);
        *(ushort4*)(plds + lp*512 + ((lane*8) ^ ((lp & 7) << 4))) = o4;
    }
    __syncthreads();

    // ---- phase 2: project o = w*32 .. w*32+31 for all 32 pixels ----
    const int l15 = lane & 15;
    const int hi  = lane >> 4;
    const int o0  = w * 32;

    bf16x8 bfr[2][8];
    #pragma unroll
    for (int n = 0; n < 2; ++n) {
        const char* rowb = plds + (n*16 + l15)*512;
        const int   m    = (l15 & 7) << 4;
        #pragma unroll
        for (int s = 0; s < 8; ++s)
            bfr[n][s] = *(const bf16x8*)(rowb + ((s*64 + hi*16) ^ m));
    }

    f32x4 acc[2][2];
    #pragma unroll
    for (int j = 0; j < 2; ++j)
        #pragma unroll
        for (int n = 0; n < 2; ++n) acc[j][n] = (f32x4){0.f,0.f,0.f,0.f};

    #pragma unroll
    for (int j = 0; j < 2; ++j) {
        const unsigned short* ab = WB + (size_t)(o0 + j*16 + l15)*CS + hi*8;
        #pragma unroll
        for (int s = 0; s < 8; ++s) {
            const bf16x8 aW = *(const bf16x8*)(ab + s*32);
            acc[j][0] = __builtin_amdgcn_mfma_f32_16x16x32_bf16(aW, bfr[0][s], acc[j][0], 0, 0, 0);
            acc[j][1] = __builtin_amdgcn_mfma_f32_16x16x32_bf16(aW, bfr[1][s], acc[j][1], 0, 0, 0);
        }
    }

    #pragma unroll
    for (int n = 0; n < 2; ++n) {
        const int gp  = gp0 + n*16 + l15;
        const int b   = gp / NOPIX;
        const int rem = gp - b*NOPIX;
        float* obase = out + (size_t)b*CS*NOPIX + rem;
        #pragma unroll
        for (int j = 0; j < 2; ++j)
            #pragma unroll
            for (int r = 0; r < 4; ++r)
                obase[(size_t)(o0 + j*16 + hi*4 + r)*NOPIX] = acc[j][n][r];
    }
}

extern "C" void kernel_launch(void* const* d_in, const int* in_sizes, int n_in,
                              void* d_out, int out_size, void* d_ws, size_t ws_size,
                              hipStream_t stream) {
    const float* x      = (const float*)d_in[0];
    const float* Wk     = (const float*)d_in[1];
    const float* Wv     = (const float*)d_in[2];
    const float* Wout   = (const float*)d_in[3];
    const float* qp     = (const float*)d_in[4];
    const float* ascale = (const float*)d_in[5];
    const float* rpb    = (const float*)d_in[6];
    float* out = (float*)d_out;

    // ws layout (bytes):
    //   cost f32 : 6,422,528
    //   V bf16   : 25,690,112
    //   WB bf16  : 131,072 | Wp: 73,728   -> ~32.3 MB
    char* ws = (char*)d_ws;
    float*          cost = (float*)(ws);
    unsigned short* V    = (unsigned short*)(ws + 6422528);
    unsigned short* WB   = (unsigned short*)(ws + 32112640);
    unsigned short* Wp   = (unsigned short*)(ws + 32243712);

    kW_prep  <<<24, 256, 0, stream>>>(Wout, Wk, Wv, qp, WB, Wp);
    k1_mfma  <<<(BATCH*NPIX)/128, 512, 0, stream>>>(x, Wp, cost, V);
    k23_fused<<<(BATCH*NOPIX)/32, 512, 0, stream>>>(cost, V, ascale, rpb, WB, out);
}

// Round 19
// 42.417 us; speedup vs baseline: 1.0160x; 1.0160x over previous
//
#include <hip/hip_runtime.h>
#include <hip/hip_bf16.h>

#define BATCH 16
#define CIN   128
#define HIMG  56
#define WIMG  56
#define NPIX  (HIMG*WIMG)      // 3136
#define CS    256
#define NQ    4
#define HOUT  28
#define WOUT  28
#define NOPIX (HOUT*WOUT)      // 784
#define QSCALE 0.17677669529663687f   // hc^-0.5 = 1/sqrt(32)
#define NCOL  288              // 256 V cols + 32 qk cols

typedef __attribute__((ext_vector_type(8))) short    bf16x8;
typedef __attribute__((ext_vector_type(4))) float    f32x4;
typedef __attribute__((ext_vector_type(4))) unsigned u32x4;

static __device__ __forceinline__ unsigned short f2bf(float f) {
    return __builtin_bit_cast(unsigned short, __float2bfloat16(f));
}
static __device__ __forceinline__ float bf2f(unsigned short u) {
    return __builtin_bit_cast(float, (unsigned)u << 16);
}
static __device__ __forceinline__ unsigned int pack2(float a, float b) {
    return (unsigned)f2bf(a) | ((unsigned)f2bf(b) << 16);
}

// ---------- kernel W: all weight prep, parallel ----------
// blocks 0..7  : Wout -> bf16
// blocks 8..15 : W' rows 0..255 (WvT repack, bf16, XOR-swizzled)
// blocks 16..23: W' rows 256..287 (q-folded Wk, per-head block)
__global__ __launch_bounds__(256) void kW_prep(
    const float* __restrict__ Wout, const float* __restrict__ Wk,
    const float* __restrict__ Wv,   const float* __restrict__ qp,
    unsigned short* __restrict__ WB, unsigned short* __restrict__ Wp)
{
    __shared__ float buf[4736];   // 18.9 KB, aliased per block role
    const int t   = threadIdx.x;
    const int blk = blockIdx.x;
    char* wp = (char*)Wp;

    if (blk < 8) {
        // ---- Wout -> bf16, coalesced ----
        const size_t base = (size_t)blk * 8192 + t;
        #pragma unroll
        for (int i = 0; i < 32; ++i)
            WB[base + i*256] = f2bf(Wout[base + i*256]);
    } else if (blk < 16) {
        // ---- WvT repack: W' row ch holds Wv[*, ch] as bf16 pairs, XOR-swizzled ----
        float (*lt)[33] = (float(*)[33])buf;           // 128*33 = 4224
        const int ch0 = (blk - 8) * 32;
        const int j = t & 31, r = t >> 5;              // r = 0..7
        #pragma unroll
        for (int pass = 0; pass < 16; ++pass) {
            const int c = r + pass*8;
            lt[c][j] = Wv[(size_t)c*CS + ch0 + j];     // coalesced 128B/row
        }
        __syncthreads();
        const int lch = t >> 3, sub = t & 7;
        const int ch  = ch0 + lch;
        const int mask = (ch & 7) << 4;
        #pragma unroll
        for (int i = 0; i < 8; ++i) {
            const int c2 = sub*8 + i;
            const unsigned u = pack2(lt[2*c2][lch], lt[2*c2+1][lch]);
            *(unsigned*)(wp + ch*256 + ((c2*4) ^ mask)) = u;
        }
    } else {
        // ---- fold for head h: Wq'[q*8+h][c] = sum_j Wk[c][h*32+j]*q[q][h*32+j]*QSCALE
        const int h = blk - 16;
        float (*wt)[36] = (float(*)[36])buf;           // 128 x 36 pad
        float* qlds = buf + 4608;                      // 4 x 32
        if (t < 128) qlds[t] = qp[(t >> 5)*CS + h*32 + (t & 31)] * QSCALE;
        {   // stage 128 rows x 32 floats, coalesced
            const int r0 = t >> 5, col = t & 31;
            #pragma unroll
            for (int pass = 0; pass < 16; ++pass) {
                const int c = r0 + pass*8;
                wt[c][col] = Wk[(size_t)c*CS + h*32 + col];
            }
        }
        __syncthreads();

        const int q  = t >> 6, c2 = t & 63;
        const int qh = q*8 + h;
        const float* r0 = wt[2*c2];
        const float* r1 = wt[2*c2 + 1];
        const float* qv = qlds + q*32;
        float d0 = 0.f, d1 = 0.f;
        #pragma unroll
        for (int j4 = 0; j4 < 32; j4 += 4) {
            const float4 a0 = *(const float4*)(r0 + j4);
            const float4 a1 = *(const float4*)(r1 + j4);
            const float4 qq = *(const float4*)(qv + j4);
            d0 = fmaf(a0.x, qq.x, d0); d0 = fmaf(a0.y, qq.y, d0);
            d0 = fmaf(a0.z, qq.z, d0); d0 = fmaf(a0.w, qq.w, d0);
            d1 = fmaf(a1.x, qq.x, d1); d1 = fmaf(a1.y, qq.y, d1);
            d1 = fmaf(a1.z, qq.z, d1); d1 = fmaf(a1.w, qq.w, d1);
        }
        *(unsigned*)(wp + (256 + qh)*256 + ((c2*4) ^ (h << 4))) = pack2(d0, d1);
    }
}

// ---------- kernel 1: fused transpose+GEMM (r11-exact, best measured) ----------
__global__ __launch_bounds__(512, 4) void k1_mfma(
    const float* __restrict__ x, const unsigned short* __restrict__ Wp,
    float* __restrict__ costO, unsigned short* __restrict__ Vout)
{
    __shared__ unsigned short Blds[NCOL*CIN];   // 73728 B

    const int t    = threadIdx.x;               // 0..511
    const int lane = t & 63;
    const int w    = t >> 6;                    // 0..7
    const int l15  = lane & 15;
    const int hi   = lane >> 4;
    const int gp0  = blockIdx.x * 128;          // global pixel base (may cross batch)
    const int gw   = gp0 + w*16;                // wave's 16-pixel row base
    const int b    = gw / NPIX;                 // 16 | NPIX, so wave stays in-batch
    const int p    = gw - b*NPIX + l15;

    // issue A loads (32 dwords, 16-lane coalesced into 64B sectors)
    float av[4][8];
    {
        const float* xb = x + (size_t)b*CIN*NPIX + (size_t)(hi*8)*NPIX + p;
        #pragma unroll
        for (int s = 0; s < 4; ++s)
            #pragma unroll
            for (int j = 0; j < 8; ++j)
                av[s][j] = xb[(size_t)(s*32 + j)*NPIX];
    }

    {   // stage B: linear copy of pre-swizzled image (L2-resident), 9 x 16B/thread
        const bf16x8* src = (const bf16x8*)Wp;
        bf16x8*       dst = (bf16x8*)Blds;
        #pragma unroll
        for (int i = 0; i < 9; ++i)
            dst[t + i*512] = src[t + i*512];
    }

    // pack A to bf16 frags while staging drains
    bf16x8 afr[4];
    #pragma unroll
    for (int s = 0; s < 4; ++s) {
        u32x4 u;
        u[0] = pack2(av[s][0], av[s][1]);
        u[1] = pack2(av[s][2], av[s][3]);
        u[2] = pack2(av[s][4], av[s][5]);
        u[3] = pack2(av[s][6], av[s][7]);
        afr[s] = __builtin_bit_cast(bf16x8, u);
    }
    __syncthreads();

    f32x4 acc[18];
    #pragma unroll
    for (int n = 0; n < 18; ++n) acc[n] = (f32x4){0.f,0.f,0.f,0.f};

    const int   mask  = (l15 & 7) << 4;
    const char* bbase = (const char*)Blds + l15*256;

    #pragma unroll
    for (int s = 0; s < 4; ++s) {
        const char* bs = bbase + ((s*64 + hi*16) ^ mask);
        #pragma unroll
        for (int n = 0; n < 18; ++n) {
            const bf16x8 bfr = *(const bf16x8*)(bs + n*4096);
            acc[n] = __builtin_amdgcn_mfma_f32_16x16x32_bf16(afr[s], bfr, acc[n], 0, 0, 0);
        }
    }

    const size_t prow0 = (size_t)gw + hi*4;
    #pragma unroll
    for (int n = 0; n < 16; ++n) {          // V cols, bf16
        unsigned short* vp = Vout + prow0*CS + n*16 + l15;
        #pragma unroll
        for (int r = 0; r < 4; ++r)
            vp[(size_t)r*CS] = f2bf(acc[n][r]);
    }
    #pragma unroll
    for (int n = 16; n < 18; ++n) {         // qk cols -> cost = exp(qk)
        float* cp = costO + prow0*32 + (n-16)*16 + l15;
        #pragma unroll
        for (int r = 0; r < 4; ++r)
            cp[(size_t)r*32] = __expf(acc[n][r]);
    }
}

// ---------- kernel 23: fused aggregation + projection (single-bf16 Wout) ----------
__global__ __launch_bounds__(512) void k23_fused(
    const float* __restrict__ cost, const unsigned short* __restrict__ V,
    const float* __restrict__ ascale, const float* __restrict__ rpb,
    const unsigned short* __restrict__ WB, float* __restrict__ out)
{
    __shared__ __align__(16) char plds[32*512];   // 16 KB pre-tile

    const int t    = threadIdx.x;
    const int lane = t & 63;
    const int w    = t >> 6;
    // bijective XCD swizzle: 392 blocks, 49 contiguous per XCD (~2 batches' V)
    const int bid  = blockIdx.x;
    const int rb   = (bid & 7) * 49 + (bid >> 3);
    const int gp0  = rb * 32;
    const int qh   = lane & 31;

    // ---- phase 1: aggregate 4 pixels per wave ----
    #pragma unroll
    for (int i = 0; i < 4; ++i) {
        const int lp  = w*4 + i;
        const int gp  = gp0 + lp;
        const int b   = gp / NOPIX;
        const int rem = gp - b*NOPIX;
        const int ho  = rem / WOUT, wo = rem - (rem/WOUT)*WOUT;

        int pk[9];
        #pragma unroll
        for (int k = 0; k < 9; ++k) {
            const int y  = 2*ho - 1 + k/3;
            const int xx = 2*wo - 1 + k%3;
            const bool v = ((unsigned)y < (unsigned)HIMG) && ((unsigned)xx < (unsigned)WIMG);
            pk[k] = v ? (y*WIMG + xx) : -1;
        }

        float cp[9];
        float den = 0.f;
        #pragma unroll
        for (int k = 0; k < 9; ++k) {
            const float s  = (pk[k] >= 0) ? cost[((size_t)(b*NPIX) + pk[k])*32 + qh] : 0.f;
            const float wd = __expf(rpb[k*32 + qh]);
            den   = fmaf(wd, s, den);
            cp[k] = wd * ascale[k*32 + qh] * s;
        }
        const float rden = 1.f / den;

        float coef[9];
        #pragma unroll
        for (int k = 0; k < 9; ++k) {
            float v = cp[k] * rden;
            v += __shfl_xor(v, 8);
            v += __shfl_xor(v, 16);
            coef[k] = __shfl(v, lane >> 3);    // lane's head h = (lane*4)/32 = lane>>3
        }

        float a0 = 0.f, a1 = 0.f, a2 = 0.f, a3 = 0.f;
        #pragma unroll
        for (int k = 0; k < 9; ++k) {
            const int p = (pk[k] >= 0) ? pk[k] : 0;   // coef==0 for invalid taps
            const ushort4 v4 = *(const ushort4*)(V + ((size_t)(b*NPIX) + p)*CS + lane*4);
            a0 = fmaf(coef[k], bf2f(v4.x), a0);
            a1 = fmaf(coef[k], bf2f(v4.y), a1);
            a2 = fmaf(coef[k], bf2f(v4.z), a2);
            a3 = fmaf(coef[k], bf2f(v4.w), a3);
        }
        ushort4 o4;
        o4.x = f2bf(a0); o4.y = f2bf(a1); o4.z = f2bf(a2); o4.w = f2bf(a3);
        *(ushort4*)(plds + lp*512 + ((lane*8) ^ ((lp & 7) << 4))) = o4;
    }
    __syncthreads();

    // ---- phase 2: project o = w*32 .. w*32+31 for all 32 pixels ----
    const int l15 = lane & 15;
    const int hi  = lane >> 4;
    const int o0  = w * 32;

    bf16x8 bfr[2][8];
    #pragma unroll
    for (int n = 0; n < 2; ++n) {
        const char* rowb = plds + (n*16 + l15)*512;
        const int   m    = (l15 & 7) << 4;
        #pragma unroll
        for (int s = 0; s < 8; ++s)
            bfr[n][s] = *(const bf16x8*)(rowb + ((s*64 + hi*16) ^ m));
    }

    f32x4 acc[2][2];
    #pragma unroll
    for (int j = 0; j < 2; ++j)
        #pragma unroll
        for (int n = 0; n < 2; ++n) acc[j][n] = (f32x4){0.f,0.f,0.f,0.f};

    #pragma unroll
    for (int j = 0; j < 2; ++j) {
        const unsigned short* ab = WB + (size_t)(o0 + j*16 + l15)*CS + hi*8;
        #pragma unroll
        for (int s = 0; s < 8; ++s) {
            const bf16x8 aW = *(const bf16x8*)(ab + s*32);
            acc[j][0] = __builtin_amdgcn_mfma_f32_16x16x32_bf16(aW, bfr[0][s], acc[j][0], 0, 0, 0);
            acc[j][1] = __builtin_amdgcn_mfma_f32_16x16x32_bf16(aW, bfr[1][s], acc[j][1], 0, 0, 0);
        }
    }

    #pragma unroll
    for (int n = 0; n < 2; ++n) {
        const int gp  = gp0 + n*16 + l15;
        const int b   = gp / NOPIX;
        const int rem = gp - b*NOPIX;
        float* obase = out + (size_t)b*CS*NOPIX + rem;
        #pragma unroll
        for (int j = 0; j < 2; ++j)
            #pragma unroll
            for (int r = 0; r < 4; ++r)
                obase[(size_t)(o0 + j*16 + hi*4 + r)*NOPIX] = acc[j][n][r];
    }
}

extern "C" void kernel_launch(void* const* d_in, const int* in_sizes, int n_in,
                              void* d_out, int out_size, void* d_ws, size_t ws_size,
                              hipStream_t stream) {
    const float* x      = (const float*)d_in[0];
    const float* Wk     = (const float*)d_in[1];
    const float* Wv     = (const float*)d_in[2];
    const float* Wout   = (const float*)d_in[3];
    const float* qp     = (const float*)d_in[4];
    const float* ascale = (const float*)d_in[5];
    const float* rpb    = (const float*)d_in[6];
    float* out = (float*)d_out;

    // ws layout (bytes):
    //   cost f32 : 6,422,528
    //   V bf16   : 25,690,112
    //   WB bf16  : 131,072 | Wp: 73,728   -> ~32.3 MB
    char* ws = (char*)d_ws;
    float*          cost = (float*)(ws);
    unsigned short* V    = (unsigned short*)(ws + 6422528);
    unsigned short* WB   = (unsigned short*)(ws + 32112640);
    unsigned short* Wp   = (unsigned short*)(ws + 32243712);

    kW_prep  <<<24, 256, 0, stream>>>(Wout, Wk, Wv, qp, WB, Wp);
    k1_mfma  <<<(BATCH*NPIX)/128, 512, 0, stream>>>(x, Wp, cost, V);
    k23_fused<<<(BATCH*NOPIX)/32, 512, 0, stream>>>(cost, V, ascale, rpb, WB, out);
}